// Round 8
// baseline (30.305 us; speedup 1.0000x reference)
//
#include <hip/hip_runtime.h>

#define NB    32
#define NT    8192
#define NF    128
#define NOUT  1024
#define NSEG  256          // 32-row segments per batch
#define NGRP  64           // 128-row groups per batch
#define TILE  64           // outputs per phase-2 tile
#define NTILE (NOUT/TILE)  // 16 tiles per batch

__device__ __forceinline__ float4 f4add(float4 a, float4 b) {
  return make_float4(a.x + b.x, a.y + b.y, a.z + b.z, a.w + b.w);
}
__device__ __forceinline__ float4 f4sub(float4 a, float4 b) {
  return make_float4(a.x - b.x, a.y - b.y, a.z - b.z, a.w - b.w);
}

// Phase 1 (R5-proven, unchanged): one block per (b, 128-row group):
// 4x 32-row seg sums + 1x 128-row group sum. 2048 blocks.
__global__ __launch_bounds__(256) void seg_sums(const float* __restrict__ x,
                                                const int* __restrict__ lengths,
                                                float* __restrict__ S32,
                                                float* __restrict__ S128) {
  const int blk = blockIdx.x;       // b * NGRP + g
  const int b   = blk >> 6;
  const int g   = blk & 63;
  const int len = lengths[b];
  if (g * 128 >= len) return;       // rows never consumed

  const int tid = threadIdx.x;
  const int fl  = tid & 31;
  const int tl  = tid >> 5;         // rows [16*tl, 16*tl+16)

  const float4* xp =
      reinterpret_cast<const float4*>(x + (size_t)b * NT * NF +
                                      (size_t)(g * 128) * NF) + fl;
  float4 acc = make_float4(0.f, 0.f, 0.f, 0.f);
  #pragma unroll
  for (int r = 0; r < 16; ++r)
    acc = f4add(acc, xp[(tl * 16 + r) * 32]);

  __shared__ float4 red[8][32];
  red[tl][fl] = acc;
  __syncthreads();
  if (tl < 4) {                     // 32-row segment sums
    float4 s = f4add(red[2 * tl][fl], red[2 * tl + 1][fl]);
    reinterpret_cast<float4*>(S32 + ((size_t)b * NSEG + g * 4 + tl) * NF)[fl] = s;
  } else if (tl == 4) {             // 128-row group sum
    float4 s = f4add(f4add(red[0][fl], red[1][fl]),
                     f4add(red[2][fl], red[3][fl]));
    s = f4add(s, f4add(f4add(red[4][fl], red[5][fl]),
                       f4add(red[6][fl], red[7][fl])));
    reinterpret_cast<float4*>(S128 + ((size_t)b * NGRP + g) * NF)[fl] = s;
  }
}

// Phase 2 (R3-verified TILE=64 body): one block per (b, 64-output tile);
// 8 t-lanes own 8 outputs each. 512 blocks, bijective XCD swizzle.
__global__ __launch_bounds__(256) void window_avg(const float* __restrict__ x,
                                                  const int* __restrict__ lengths,
                                                  const float* __restrict__ S32,
                                                  const float* __restrict__ S128,
                                                  float* __restrict__ out) {
  const int bid  = blockIdx.x;
  const int wg   = ((bid & 7) << 6) + (bid >> 3);  // 512 % 8 == 0 -> bijective
  const int b    = wg >> 4;
  const int tile = wg & (NTILE - 1);
  const int len  = lengths[b];
  const int W    = len - NOUT + 1;                 // [2, 7169]
  const int t0   = tile * TILE;
  const int p1   = t0 + W;                         // <= 960 + 7169 = 8129
  const int s_lo = t0 >> 5;
  const int s_hi = p1 >> 5;
  const int g_lo = (t0 + 127) >> 7;
  const int g_hi = p1 >> 7;

  const int tid = threadIdx.x;
  const int fl  = tid & 31;
  const int tl  = tid >> 5;                        // owns outputs t0+8*tl .. +7

  const float4* xb =
      reinterpret_cast<const float4*>(x + (size_t)b * NT * NF) + fl;
  const float4* S32b =
      reinterpret_cast<const float4*>(S32 + (size_t)b * NSEG * NF) + fl;
  const float4* S128b =
      reinterpret_cast<const float4*>(S128 + (size_t)b * NGRP * NF) + fl;

  // Cooperative A0 = cs[p1] - cs[t0], hierarchical (128-groups + 32-segs)
  float4 acc = make_float4(0.f, 0.f, 0.f, 0.f);
  if (g_hi > g_lo) {
    for (int s = s_lo + tl; s < 4 * g_lo; s += 8)   // leading 32-segs (<=3)
      acc = f4add(acc, S32b[s * 32]);
    for (int g = g_lo + tl; g < g_hi; g += 8)       // full 128-groups
      acc = f4add(acc, S128b[g * 32]);
    for (int s = 4 * g_hi + tl; s < s_hi; s += 8)   // trailing 32-segs (<=3)
      acc = f4add(acc, S32b[s * 32]);
  } else {
    for (int s = s_lo + tl; s < s_hi; s += 8)       // short window
      acc = f4add(acc, S32b[s * 32]);
  }
  for (int j = (s_hi << 5) + tl; j < p1; j += 8)    // remainder rows (<32)
    acc = f4add(acc, xb[j * 32]);

  __shared__ float4 red[8][32];
  red[tl][fl] = acc;
  __syncthreads();
  float4 A = make_float4(0.f, 0.f, 0.f, 0.f);
  #pragma unroll
  for (int k = 0; k < 8; ++k) A = f4add(A, red[k][fl]);
  __syncthreads();

  // Per-lane deltas D[tl] = A(t0+8(tl+1)) - A(t0+8tl); lane 7's never
  // consumed (max read here: p1 + 55 <= 8184).
  float4 D = make_float4(0.f, 0.f, 0.f, 0.f);
  if (tl < 7) {
    const int baseLo = t0 + 8 * tl;
    const int baseHi = p1 + 8 * tl;
    #pragma unroll
    for (int j = 0; j < 8; ++j)
      D = f4add(D, f4sub(xb[(baseHi + j) * 32], xb[(baseLo + j) * 32]));
  }
  red[tl][fl] = D;
  __syncthreads();
  #pragma unroll
  for (int k = 0; k < 7; ++k)
    if (k < tl) A = f4add(A, red[k][fl]);           // exclusive prefix

  const float invW  = 1.0f / (float)W;
  const int   tbase = t0 + 8 * tl;
  float4* ob =
      reinterpret_cast<float4*>(out + ((size_t)b * NOUT + tbase) * NF) + fl;

  #pragma unroll
  for (int i = 0; i < 8; ++i) {
    ob[i * 32] = make_float4(A.x * invW, A.y * invW, A.z * invW, A.w * invW);
    if (i < 7) {  // last update dead; max read idx = t0+62+W <= 8191
      float4 h = xb[(tbase + i + W) * 32];
      float4 l = xb[(tbase + i) * 32];
      A = f4add(A, f4sub(h, l));
    }
  }
}

extern "C" void kernel_launch(void* const* d_in, const int* in_sizes, int n_in,
                              void* d_out, int out_size, void* d_ws, size_t ws_size,
                              hipStream_t stream) {
  const float* x       = (const float*)d_in[0];
  const int*   lengths = (const int*)d_in[1];
  float*       S32     = (float*)d_ws;                          // 4 MB
  float*       S128    = (float*)d_ws + (size_t)NB * NSEG * NF; // +1 MB
  float*       out     = (float*)d_out;

  hipLaunchKernelGGL(seg_sums, dim3(NB * NGRP), dim3(256), 0, stream,
                     x, lengths, S32, S128);
  hipLaunchKernelGGL(window_avg, dim3(NB * NTILE), dim3(256), 0, stream,
                     x, lengths, S32, S128, out);
}

// Round 9
// 29.143 us; speedup vs baseline: 1.0399x; 1.0399x over previous
//
#include <hip/hip_runtime.h>

#define NB    32
#define NT    8192
#define NF    128
#define NOUT  1024
#define NSEG  256          // 32-row segments per batch
#define NGRP  64           // 128-row groups per batch
#define TILE  32           // outputs per phase-2 block
#define NTILE (NOUT/TILE)  // 32 tiles per batch

__device__ __forceinline__ float4 f4add(float4 a, float4 b) {
  return make_float4(a.x + b.x, a.y + b.y, a.z + b.z, a.w + b.w);
}
__device__ __forceinline__ float4 f4sub(float4 a, float4 b) {
  return make_float4(a.x - b.x, a.y - b.y, a.z - b.z, a.w - b.w);
}

// Phase 1 (R5-proven, byte-for-byte): one block per (b, 128-row group):
// 4x 32-row seg sums + 1x 128-row group sum. 2048 blocks.
__global__ __launch_bounds__(256) void seg_sums(const float* __restrict__ x,
                                                const int* __restrict__ lengths,
                                                float* __restrict__ S32,
                                                float* __restrict__ S128) {
  const int blk = blockIdx.x;       // b * NGRP + g
  const int b   = blk >> 6;
  const int g   = blk & 63;
  const int len = lengths[b];
  if (g * 128 >= len) return;       // rows never consumed

  const int tid = threadIdx.x;
  const int fl  = tid & 31;
  const int tl  = tid >> 5;         // rows [16*tl, 16*tl+16)

  const float4* xp =
      reinterpret_cast<const float4*>(x + (size_t)b * NT * NF +
                                      (size_t)(g * 128) * NF) + fl;
  float4 acc = make_float4(0.f, 0.f, 0.f, 0.f);
  #pragma unroll
  for (int r = 0; r < 16; ++r)
    acc = f4add(acc, xp[(tl * 16 + r) * 32]);

  __shared__ float4 red[8][32];
  red[tl][fl] = acc;
  __syncthreads();
  if (tl < 4) {                     // 32-row segment sums
    float4 s = f4add(red[2 * tl][fl], red[2 * tl + 1][fl]);
    reinterpret_cast<float4*>(S32 + ((size_t)b * NSEG + g * 4 + tl) * NF)[fl] = s;
  } else if (tl == 4) {             // 128-row group sum
    float4 s = f4add(f4add(red[0][fl], red[1][fl]),
                     f4add(red[2][fl], red[3][fl]));
    s = f4add(s, f4add(f4add(red[4][fl], red[5][fl]),
                       f4add(red[6][fl], red[7][fl])));
    reinterpret_cast<float4*>(S128 + ((size_t)b * NGRP + g) * NF)[fl] = s;
  }
}

// Phase 2 (R5 structure, TILE=32, 1024 blocks) + boundary-row register reuse:
// the D-prefix loop and the slide loop now share ONE set of loads.
__global__ __launch_bounds__(256) void window_avg(const float* __restrict__ x,
                                                  const int* __restrict__ lengths,
                                                  const float* __restrict__ S32,
                                                  const float* __restrict__ S128,
                                                  float* __restrict__ out) {
  const int wg   = ((blockIdx.x & 7) << 7) + (blockIdx.x >> 3);  // XCD swizzle
  const int b    = wg >> 5;
  const int tile = wg & (NTILE - 1);
  const int len  = lengths[b];
  const int W    = len - NOUT + 1;  // [2, 7169]
  const int t0   = tile * TILE;
  const int p1   = t0 + W;          // <= 992 + 7169 = 8161
  const int s_hi = p1 >> 5;
  const int g_lo = (t0 + 127) >> 7;
  const int g_hi = p1 >> 7;

  const int tid = threadIdx.x;
  const int fl  = tid & 31;
  const int tl  = tid >> 5;         // owns outputs t0+4*tl .. +3

  const float4* xb =
      reinterpret_cast<const float4*>(x + (size_t)b * NT * NF) + fl;
  const float4* S32b =
      reinterpret_cast<const float4*>(S32 + (size_t)b * NSEG * NF) + fl;
  const float4* S128b =
      reinterpret_cast<const float4*>(S128 + (size_t)b * NGRP * NF) + fl;

  // Cooperative A0 = cs[p1] - cs[t0], hierarchical (128-groups + 32-segs)
  float4 acc = make_float4(0.f, 0.f, 0.f, 0.f);
  if (g_hi > g_lo) {
    for (int s = tile + tl; s < 4 * g_lo; s += 8)   // leading 32-segs (<=3)
      acc = f4add(acc, S32b[s * 32]);
    for (int g = g_lo + tl; g < g_hi; g += 8)       // full 128-groups
      acc = f4add(acc, S128b[g * 32]);
    for (int s = 4 * g_hi + tl; s < s_hi; s += 8)   // trailing 32-segs (<=3)
      acc = f4add(acc, S32b[s * 32]);
  } else {
    for (int s = tile + tl; s < s_hi; s += 8)       // short window
      acc = f4add(acc, S32b[s * 32]);
  }
  for (int j = (s_hi << 5) + tl; j < p1; j += 8)    // remainder rows (<32)
    acc = f4add(acc, xb[j * 32]);

  __shared__ float4 red[8][32];
  red[tl][fl] = acc;
  __syncthreads();
  float4 A = make_float4(0.f, 0.f, 0.f, 0.f);
  #pragma unroll
  for (int k = 0; k < 8; ++k) A = f4add(A, red[k][fl]);
  __syncthreads();

  // Preload boundary rows ONCE; reused by both D-prefix and slide loops.
  // Lane tl needs lo rows [t0+4tl .. +3] and hi rows [p1+4tl .. +3].
  // Lane 7 skips j=3 (row p1+31 can be 8192 = OOB; its D is unused and
  // its slide needs only j<3).
  const int baseLo = t0 + 4 * tl;
  const int baseHi = p1 + 4 * tl;
  const int jmax   = (tl < 7) ? 4 : 3;
  float4 lo[4], hi[4];
  #pragma unroll
  for (int j = 0; j < 4; ++j) {
    if (j < jmax) {
      lo[j] = xb[(baseLo + j) * 32];
      hi[j] = xb[(baseHi + j) * 32];
    } else {
      lo[j] = make_float4(0.f, 0.f, 0.f, 0.f);
      hi[j] = make_float4(0.f, 0.f, 0.f, 0.f);
    }
  }

  float4 D = make_float4(0.f, 0.f, 0.f, 0.f);
  if (tl < 7) {
    #pragma unroll
    for (int j = 0; j < 4; ++j)
      D = f4add(D, f4sub(hi[j], lo[j]));
  }
  red[tl][fl] = D;
  __syncthreads();
  #pragma unroll
  for (int k = 0; k < 7; ++k)
    if (k < tl) A = f4add(A, red[k][fl]);   // exclusive prefix -> A(t0+4*tl)

  const float invW = 1.0f / (float)W;
  float4* ob =
      reinterpret_cast<float4*>(out + ((size_t)b * NOUT + baseLo) * NF) + fl;

  #pragma unroll
  for (int i = 0; i < 4; ++i) {
    ob[i * 32] = make_float4(A.x * invW, A.y * invW, A.z * invW, A.w * invW);
    if (i < 3)                              // last update dead
      A = f4add(A, f4sub(hi[i], lo[i]));
  }
}

extern "C" void kernel_launch(void* const* d_in, const int* in_sizes, int n_in,
                              void* d_out, int out_size, void* d_ws, size_t ws_size,
                              hipStream_t stream) {
  const float* x       = (const float*)d_in[0];
  const int*   lengths = (const int*)d_in[1];
  float*       S32     = (float*)d_ws;                          // 4 MB
  float*       S128    = (float*)d_ws + (size_t)NB * NSEG * NF; // +1 MB
  float*       out     = (float*)d_out;

  hipLaunchKernelGGL(seg_sums, dim3(NB * NGRP), dim3(256), 0, stream,
                     x, lengths, S32, S128);
  hipLaunchKernelGGL(window_avg, dim3(NB * NTILE), dim3(256), 0, stream,
                     x, lengths, S32, S128, out);
}